// Round 1
// baseline (890.130 us; speedup 1.0000x reference)
//
#include <hip/hip_runtime.h>
#include <math.h>

#define PI_F 3.14159265358979323846f

// PKVA ladder filter: concat(half[::-1], half)
__constant__ float c_pkva[12] = {
  -0.0144f, 0.0272f, -0.0526f, 0.0972f, -0.193f, 0.63f,
   0.63f, -0.193f, 0.0972f, -0.0526f, 0.0272f, -0.0144f
};

// Meyer-style smooth lowpass 1D profile at frequency index k of an n-point DFT
__device__ __forceinline__ float phi_dev(int k, int n) {
  int kk = (k < n - k) ? k : (n - k);
  float w = 2.0f * PI_F * (float)kk / (float)n;
  float s = (w - PI_F / 3.0f) * (3.0f / PI_F);
  s = fminf(fmaxf(s, 0.0f), 1.0f);
  float s2 = s * s;
  float beta = s2 * s2 * (35.0f - 84.0f * s + 70.0f * s2 - 20.0f * s2 * s);
  return __cosf(0.5f * PI_F * beta);
}

// ---------------------------------------------------------------------------
// Batched row FFT (Stockham radix-2 autosort in LDS). One block = one row.
// LMODE: 0 = load real, 1 = load complex, 2 = load complex * Hm(highpass mask)
// SMODE: 0 = store complex, 1 = store real part
// dirsign: -1 forward, +1 inverse. scale applied at load.
// blockIdx.x = img*N + r  (r needed for the mask row index)
// ---------------------------------------------------------------------------
template <int N, int LMODE, int SMODE>
__global__ void __launch_bounds__(N / 2)
fft_rows_k(const void* __restrict__ vin, void* __restrict__ vout,
           float dirsign, float scale) {
  __shared__ float2 sbuf[2][N];
  const int tid = threadIdx.x;
  const int row = blockIdx.x;
  const int r = row & (N - 1);

  if (LMODE == 0) {
    const float* in = (const float*)vin;
    for (int i = tid; i < N; i += N / 2)
      sbuf[0][i] = make_float2(in[(size_t)row * N + i] * scale, 0.0f);
  } else if (LMODE == 1) {
    const float2* in = (const float2*)vin;
    for (int i = tid; i < N; i += N / 2) {
      float2 v = in[(size_t)row * N + i];
      sbuf[0][i] = make_float2(v.x * scale, v.y * scale);
    }
  } else {
    const float2* in = (const float2*)vin;
    float pr = phi_dev(r, N);
    for (int i = tid; i < N; i += N / 2) {
      float lm = pr * phi_dev(i, N);
      float hm = sqrtf(fmaxf(1.0f - lm * lm, 0.0f));
      float m = hm * scale;
      float2 v = in[(size_t)row * N + i];
      sbuf[0][i] = make_float2(v.x * m, v.y * m);
    }
  }
  __syncthreads();

  int cur = 0;
#pragma unroll
  for (int Ns = 1; Ns < N; Ns <<= 1) {
    int j = tid;
    int base = j & (Ns - 1);
    float2 v0 = sbuf[cur][j];
    float2 v1 = sbuf[cur][j + N / 2];
    float ang = dirsign * (2.0f * PI_F) * (float)base / (float)(2 * Ns);
    float sn, cs;
    __sincosf(ang, &sn, &cs);
    float2 t = make_float2(v1.x * cs - v1.y * sn, v1.x * sn + v1.y * cs);
    int idxD = ((j & ~(Ns - 1)) << 1) | base;
    cur ^= 1;
    sbuf[cur][idxD]      = make_float2(v0.x + t.x, v0.y + t.y);
    sbuf[cur][idxD + Ns] = make_float2(v0.x - t.x, v0.y - t.y);
    __syncthreads();
  }

  if (SMODE == 0) {
    float2* outp = (float2*)vout;
    for (int i = tid; i < N; i += N / 2)
      outp[(size_t)row * N + i] = sbuf[cur][i];
  } else {
    float* outp = (float*)vout;
    for (int i = tid; i < N; i += N / 2)
      outp[(size_t)row * N + i] = sbuf[cur][i].x;
  }
}

// Batched square transpose (per-image), complex
__global__ void transpose_k(const float2* __restrict__ in,
                            float2* __restrict__ out, int N) {
  __shared__ float2 tile[32][33];
  int img = blockIdx.z;
  size_t base = (size_t)img * N * N;
  int x = blockIdx.x * 32 + threadIdx.x;
  int y0 = blockIdx.y * 32;
  for (int j = threadIdx.y; j < 32; j += 8)
    tile[j][threadIdx.x] = in[base + (size_t)(y0 + j) * N + x];
  __syncthreads();
  int x2 = blockIdx.y * 32 + threadIdx.x;
  int y2 = blockIdx.x * 32;
  for (int j = threadIdx.y; j < 32; j += 8)
    out[base + (size_t)(y2 + j) * N + x2] = tile[threadIdx.x][j];
}

// Frequency-domain decimation by 2: out[r,c] = 1/4 sum_{a,b} Lm*In at aliases.
// Works on transposed spectra (masks symmetric). N = input size, output N/2.
__global__ void alias_k(const float2* __restrict__ in, float2* __restrict__ out,
                        int N, int lgN2) {
  int idx = blockIdx.x * 256 + threadIdx.x;
  int N2 = N >> 1;
  int c = idx & (N2 - 1);
  int r = (idx >> lgN2) & (N2 - 1);
  int img = idx >> (2 * lgN2);
  float pr0 = phi_dev(r, N), pr1 = phi_dev(r + N2, N);
  float pc0 = phi_dev(c, N), pc1 = phi_dev(c + N2, N);
  size_t base = (size_t)img * N * N;
  float2 v00 = in[base + (size_t)r * N + c];
  float2 v01 = in[base + (size_t)r * N + c + N2];
  float2 v10 = in[base + (size_t)(r + N2) * N + c];
  float2 v11 = in[base + (size_t)(r + N2) * N + c + N2];
  float m00 = pr0 * pc0, m01 = pr0 * pc1, m10 = pr1 * pc0, m11 = pr1 * pc1;
  float2 o;
  o.x = 0.25f * (v00.x * m00 + v01.x * m01 + v10.x * m10 + v11.x * m11);
  o.y = 0.25f * (v00.y * m00 + v01.y * m01 + v10.y * m10 + v11.y * m11);
  out[((size_t)img << (2 * lgN2)) + ((size_t)r << lgN2) + c] = o;
}

// ---------------------------------------------------------------------------
// DFB fan split, axis = -1 (split along W). Fused s+d in one kernel per row.
// Input: (nimgS, H, W) flat. Output: s at [0..halfT), d at [halfT..2*halfT),
// each shaped (nimgS, H, W/2). blockIdx.x = n*H + r.
// xs(c) = sgn_r * x[r, (c+par) mod W], par = r&1, sgn = 1-2*par
// d[j] = xs(2j+1) - sum_k f[k]*xs(2*((j-6+k) mod W2))
// s[j] = xs(2j)   + 0.5*sum_k f[k]*d[(j-6+k) mod W2]
// ---------------------------------------------------------------------------
__global__ void __launch_bounds__(256)
fs_row_k(const float* __restrict__ x, float* __restrict__ outb,
         int lgH, int lgW, int halfT) {
  __shared__ float xs[1024];
  __shared__ float db[512];
  int H = 1 << lgH, W = 1 << lgW, W2 = W >> 1;
  int nr = blockIdx.x;
  int r = nr & (H - 1);
  int par = r & 1;
  float sgn = par ? -1.0f : 1.0f;
  const float* xrow = x + (size_t)nr * W;
  for (int c = threadIdx.x; c < W; c += 256)
    xs[c] = sgn * xrow[(c + par) & (W - 1)];
  __syncthreads();
  float* outs = outb + (size_t)nr * W2;
  float* outd = outb + halfT + (size_t)nr * W2;
  for (int j = threadIdx.x; j < W2; j += 256) {
    float acc = 0.0f;
#pragma unroll
    for (int k = 0; k < 12; k++)
      acc += c_pkva[k] * xs[2 * ((j - 6 + k + W2) & (W2 - 1))];
    float dv = xs[2 * j + 1] - acc;
    db[j] = dv;
    outd[j] = dv;
  }
  __syncthreads();
  for (int j = threadIdx.x; j < W2; j += 256) {
    float acc = 0.0f;
#pragma unroll
    for (int k = 0; k < 12; k++)
      acc += c_pkva[k] * db[(j - 6 + k + W2) & (W2 - 1)];
    outs[j] = xs[2 * j] + 0.5f * acc;
  }
}

// DFB fan split, axis = -2 (split along H): d pass.
// Input (nimgS,H,W), outputs shaped (nimgS,H/2,W). par/sgn from column parity.
__global__ void __launch_bounds__(256)
fs_col_d_k(const float* __restrict__ x, float* __restrict__ outb,
           int lgH, int lgW, int halfT) {
  int H = 1 << lgH, W = 1 << lgW, H2 = H >> 1;
  int idx = blockIdx.x * 256 + threadIdx.x;
  int c = idx & (W - 1);
  int i = (idx >> lgW) & (H2 - 1);
  int n = idx >> (lgW + lgH - 1);
  int par = c & 1;
  float sgn = par ? -1.0f : 1.0f;
  const float* xim = x + ((size_t)n << (lgH + lgW));
  float p1 = xim[(((2 * i + 1 + par) & (H - 1)) << lgW) + c];
  float acc = 0.0f;
#pragma unroll
  for (int k = 0; k < 12; k++) {
    int m = (i - 6 + k + H2) & (H2 - 1);
    acc += c_pkva[k] * xim[(((2 * m + par) & (H - 1)) << lgW) + c];
  }
  outb[halfT + idx] = sgn * (p1 - acc);
}

// DFB fan split, axis = -2: s pass (reads d written by fs_col_d_k).
__global__ void __launch_bounds__(256)
fs_col_s_k(const float* __restrict__ x, float* __restrict__ outb,
           int lgH, int lgW, int halfT) {
  int H = 1 << lgH, W = 1 << lgW, H2 = H >> 1;
  int idx = blockIdx.x * 256 + threadIdx.x;
  int c = idx & (W - 1);
  int i = (idx >> lgW) & (H2 - 1);
  int n = idx >> (lgW + lgH - 1);
  int par = c & 1;
  float sgn = par ? -1.0f : 1.0f;
  const float* xim = x + ((size_t)n << (lgH + lgW));
  float p0 = sgn * xim[(((2 * i + par) & (H - 1)) << lgW) + c];
  float acc = 0.0f;
#pragma unroll
  for (int k = 0; k < 12; k++) {
    int m = (i - 6 + k + H2) & (H2 - 1);
    acc += c_pkva[k] * outb[halfT + ((((n << (lgH - 1)) + m) << lgW) + c)];
  }
  outb[idx] = p0 + 0.5f * acc;
}

__global__ void fill_err_k(float* out) {
  out[threadIdx.x] = 1.0e9f;  // unmistakable sentinel: workspace too small
}

// ---------------------------------------------------------------------------
extern "C" void kernel_launch(void* const* d_in, const int* in_sizes, int n_in,
                              void* d_out, int out_size, void* d_ws, size_t ws_size,
                              hipStream_t stream) {
  const float* x = (const float*)d_in[0];
  float* out = (float*)d_out;
  char* ws = (char*)d_ws;

  const size_t NEED = 312475648ull;  // bufA+bufB (2x134MB) + spec2/3/4
  if (ws_size < NEED) {
    fill_err_k<<<dim3(1), dim3(256), 0, stream>>>(out);
    return;
  }

  float2* bufA  = (float2*)(ws);                 // 134217728 B
  float2* bufB  = (float2*)(ws + 134217728);     // 134217728 B
  float2* spec2 = (float2*)(ws + 268435456);     // 33554432 B  (16 x 512^2)
  float2* spec3 = (float2*)(ws + 301989888);     // 8388608 B   (16 x 256^2)
  float2* spec4 = (float2*)(ws + 310378496);     // 2097152 B   (16 x 128^2)

  // Output offsets (floats): [lp128 | dfb(band3,n=2) | dfb(band2,n=3) | dfb(band1,n=4)]
  float* out0 = out;             // 262144
  float* out1 = out + 262144;    // 1048576
  float* out2 = out + 1310720;   // 4194304
  float* out3 = out + 5505024;   // 16777216

  // ---- Level 1: forward FFT2 of x; bufA ends holding X1^T (transposed spectrum)
  fft_rows_k<1024, 0, 0><<<dim3(16384), dim3(512), 0, stream>>>((const void*)x, (void*)bufA, -1.0f, 1.0f);
  transpose_k<<<dim3(32, 32, 16), dim3(32, 8), 0, stream>>>(bufA, bufB, 1024);
  fft_rows_k<1024, 1, 0><<<dim3(16384), dim3(512), 0, stream>>>((const void*)bufB, (void*)bufA, -1.0f, 1.0f);
  // alias-decimate (with Lm) -> spec2 = X2^T (512^2)
  alias_k<<<dim3(16384), dim3(256), 0, stream>>>(bufA, spec2, 1024, 9);
  // band1 = ifft2(X1 * Hm): G(T(G(X1^T * Hm)))
  fft_rows_k<1024, 2, 0><<<dim3(16384), dim3(512), 0, stream>>>((const void*)bufA, (void*)bufB, 1.0f, 1.0f / 1024.0f);
  transpose_k<<<dim3(32, 32, 16), dim3(32, 8), 0, stream>>>(bufB, bufA, 1024);
  float* band1 = (float*)bufB;
  fft_rows_k<1024, 1, 1><<<dim3(16384), dim3(512), 0, stream>>>((const void*)bufA, (void*)band1, 1.0f, 1.0f / 1024.0f);

  // DFB n=4 on band1 (1,16,1024,1024) -> (16,16,256,256) into out3
  float* dfb0 = (float*)bufA;
  float* dfb1 = dfb0 + 16777216;
  fs_row_k  <<<dim3(16384), dim3(256), 0, stream>>>(band1, dfb0, 10, 10, 8388608);
  fs_col_d_k<<<dim3(32768), dim3(256), 0, stream>>>(dfb0, dfb1, 10, 9, 8388608);
  fs_col_s_k<<<dim3(32768), dim3(256), 0, stream>>>(dfb0, dfb1, 10, 9, 8388608);
  fs_row_k  <<<dim3(32768), dim3(256), 0, stream>>>(dfb1, dfb0, 9, 9, 8388608);
  fs_col_d_k<<<dim3(32768), dim3(256), 0, stream>>>(dfb0, out3, 9, 8, 8388608);
  fs_col_s_k<<<dim3(32768), dim3(256), 0, stream>>>(dfb0, out3, 9, 8, 8388608);

  // ---- Level 2
  alias_k<<<dim3(4096), dim3(256), 0, stream>>>(spec2, spec3, 512, 8);
  fft_rows_k<512, 2, 0><<<dim3(8192), dim3(256), 0, stream>>>((const void*)spec2, (void*)bufA, 1.0f, 1.0f / 512.0f);
  transpose_k<<<dim3(16, 16, 16), dim3(32, 8), 0, stream>>>(bufA, bufB, 512);
  float* band2 = (float*)bufA;
  fft_rows_k<512, 1, 1><<<dim3(8192), dim3(256), 0, stream>>>((const void*)bufB, (void*)band2, 1.0f, 1.0f / 512.0f);
  // DFB n=3 on band2 (1,16,512,512) -> (8,16,256,128) into out2
  float* t2 = (float*)bufB;
  fs_row_k  <<<dim3(8192),  dim3(256), 0, stream>>>(band2, t2, 9, 9, 2097152);
  fs_col_d_k<<<dim3(8192),  dim3(256), 0, stream>>>(t2, (float*)bufA, 9, 8, 2097152);
  fs_col_s_k<<<dim3(8192),  dim3(256), 0, stream>>>(t2, (float*)bufA, 9, 8, 2097152);
  fs_row_k  <<<dim3(16384), dim3(256), 0, stream>>>((float*)bufA, out2, 8, 8, 2097152);

  // ---- Level 3
  alias_k<<<dim3(1024), dim3(256), 0, stream>>>(spec3, spec4, 256, 7);
  fft_rows_k<256, 2, 0><<<dim3(4096), dim3(128), 0, stream>>>((const void*)spec3, (void*)bufA, 1.0f, 1.0f / 256.0f);
  transpose_k<<<dim3(8, 8, 16), dim3(32, 8), 0, stream>>>(bufA, bufB, 256);
  float* band3 = (float*)bufA;
  fft_rows_k<256, 1, 1><<<dim3(4096), dim3(128), 0, stream>>>((const void*)bufB, (void*)band3, 1.0f, 1.0f / 256.0f);
  // DFB n=2 on band3 (1,16,256,256) -> (4,16,128,128) into out1
  fs_row_k  <<<dim3(4096), dim3(256), 0, stream>>>(band3, (float*)bufB, 8, 8, 524288);
  fs_col_d_k<<<dim3(2048), dim3(256), 0, stream>>>((float*)bufB, out1, 8, 7, 524288);
  fs_col_s_k<<<dim3(2048), dim3(256), 0, stream>>>((float*)bufB, out1, 8, 7, 524288);

  // ---- Final lowpass: out0 = ifft2(X4^T) at 128^2
  fft_rows_k<128, 1, 0><<<dim3(2048), dim3(64), 0, stream>>>((const void*)spec4, (void*)bufA, 1.0f, 1.0f / 128.0f);
  transpose_k<<<dim3(4, 4, 16), dim3(32, 8), 0, stream>>>(bufA, bufB, 128);
  fft_rows_k<128, 1, 1><<<dim3(2048), dim3(64), 0, stream>>>((const void*)bufB, (void*)out0, 1.0f, 1.0f / 128.0f);
}

// Round 2
// 789.424 us; speedup vs baseline: 1.1276x; 1.1276x over previous
//
#include <hip/hip_runtime.h>
#include <math.h>

#define PI_F 3.14159265358979323846f

__constant__ float c_pkva[12] = {
  -0.0144f, 0.0272f, -0.0526f, 0.0972f, -0.193f, 0.63f,
   0.63f, -0.193f, 0.0972f, -0.0526f, 0.0272f, -0.0144f
};

constexpr int ilog2c(int n) { int l = 0; while (n > 1) { n >>= 1; ++l; } return l; }

__device__ __forceinline__ float phi_dev(int k, int n) {
  int kk = (k < n - k) ? k : (n - k);
  float w = 2.0f * PI_F * (float)kk / (float)n;
  float s = (w - PI_F / 3.0f) * (3.0f / PI_F);
  s = fminf(fmaxf(s, 0.0f), 1.0f);
  float s2 = s * s;
  float beta = s2 * s2 * (35.0f - 84.0f * s + 70.0f * s2 - 20.0f * s2 * s);
  return __cosf(0.5f * PI_F * beta);
}

__device__ __forceinline__ float2 cmul(float2 a, float2 b) {
  return make_float2(a.x * b.x - a.y * b.y, a.x * b.y + a.y * b.x);
}
__device__ __forceinline__ float2 cadd(float2 a, float2 b) { return make_float2(a.x + b.x, a.y + b.y); }
__device__ __forceinline__ float2 csub(float2 a, float2 b) { return make_float2(a.x - b.x, a.y - b.y); }

// ---------------------------------------------------------------------------
// In-LDS Stockham FFT core. Radix-4 with an optional leading radix-2 stage
// (when log2(N) is odd). NT = N/4 threads. Caller must __syncthreads() after
// filling sbuf[0]. Returns final buffer index.
// ---------------------------------------------------------------------------
template <int N, int NT>
__device__ __forceinline__ int fft_core(float2 (*sbuf)[N], float dirsign, int tid) {
  constexpr int LOG2 = ilog2c(N);
  constexpr bool LEAD2 = (LOG2 & 1);
  int cur = 0;
  if (LEAD2) {
#pragma unroll
    for (int j = tid; j < N / 2; j += NT) {
      float2 v0 = sbuf[cur][j], v1 = sbuf[cur][j + N / 2];
      sbuf[cur ^ 1][2 * j]     = cadd(v0, v1);
      sbuf[cur ^ 1][2 * j + 1] = csub(v0, v1);
    }
    cur ^= 1;
    __syncthreads();
  }
#pragma unroll
  for (int Ns = LEAD2 ? 2 : 1; Ns < N; Ns <<= 2) {
    int j = tid;  // NT == N/4
    int base = j & (Ns - 1);
    float ang = dirsign * (2.0f * PI_F) * (float)base / (float)(4 * Ns);
    float2 w1;
    __sincosf(ang, &w1.y, &w1.x);
    float2 w2 = cmul(w1, w1);
    float2 w3 = cmul(w2, w1);
    float2 v0 = sbuf[cur][j];
    float2 v1 = cmul(sbuf[cur][j + N / 4], w1);
    float2 v2 = cmul(sbuf[cur][j + N / 2], w2);
    float2 v3 = cmul(sbuf[cur][j + 3 * (N / 4)], w3);
    float2 a0 = cadd(v0, v2), a1 = csub(v0, v2);
    float2 a2 = cadd(v1, v3), a3 = csub(v1, v3);
    float2 r1 = make_float2(-dirsign * a3.y, dirsign * a3.x);  // i*dirsign*a3
    int idxD = ((j - base) << 2) + base;
    cur ^= 1;
    sbuf[cur][idxD]          = cadd(a0, a2);
    sbuf[cur][idxD + Ns]     = cadd(a1, r1);
    sbuf[cur][idxD + 2 * Ns] = csub(a0, a2);
    sbuf[cur][idxD + 3 * Ns] = csub(a1, r1);
    __syncthreads();
  }
  return cur;
}

// ---------------------------------------------------------------------------
// Batched row FFT. LMODE: 1 = complex load, 2 = complex * Hm mask.
// SMODE: 0 = complex store, 1 = real store.
// ---------------------------------------------------------------------------
template <int N, int LMODE, int SMODE>
__global__ void __launch_bounds__(N / 4)
fft_rows_k(const void* __restrict__ vin, void* __restrict__ vout,
           float dirsign, float scale) {
  constexpr int NT = N / 4;
  __shared__ float2 sbuf[2][N];
  const int tid = threadIdx.x;
  const int row = blockIdx.x;
  const int r = row & (N - 1);

  if (LMODE == 1) {
    const float2* in = (const float2*)vin;
#pragma unroll
    for (int i = tid; i < N; i += NT) {
      float2 v = in[(size_t)row * N + i];
      sbuf[0][i] = make_float2(v.x * scale, v.y * scale);
    }
  } else {
    const float2* in = (const float2*)vin;
    float pr = phi_dev(r, N);
#pragma unroll
    for (int i = tid; i < N; i += NT) {
      float lm = pr * phi_dev(i, N);
      float hm = sqrtf(fmaxf(1.0f - lm * lm, 0.0f));
      float m = hm * scale;
      float2 v = in[(size_t)row * N + i];
      sbuf[0][i] = make_float2(v.x * m, v.y * m);
    }
  }
  __syncthreads();

  int cur = fft_core<N, NT>(sbuf, dirsign, tid);

  if (SMODE == 0) {
    float2* outp = (float2*)vout;
#pragma unroll
    for (int i = tid; i < N; i += NT)
      outp[(size_t)row * N + i] = sbuf[cur][i];
  } else {
    float* outp = (float*)vout;
#pragma unroll
    for (int i = tid; i < N; i += NT)
      outp[(size_t)row * N + i] = sbuf[cur][i].x;
  }
}

// ---------------------------------------------------------------------------
// First forward FFT on real input: two rows (2r, 2r+1) packed as one complex
// FFT, untangled via Hermitian symmetry. Writes both full complex spectra.
// blockIdx.x = img*(N/2) + r.
// ---------------------------------------------------------------------------
template <int N>
__global__ void __launch_bounds__(N / 4)
rfft_pairs_k(const float* __restrict__ in, float2* __restrict__ out) {
  constexpr int NT = N / 4;
  __shared__ float2 sbuf[2][N];
  const int tid = threadIdx.x;
  const int img = blockIdx.x >> (ilog2c(N) - 1);
  const int r = blockIdx.x & (N / 2 - 1);
  const size_t row0 = (size_t)img * N + 2 * r;
  const float* p0 = in + row0 * N;
  const float* p1 = p0 + N;

#pragma unroll
  for (int i = tid; i < N; i += NT)
    sbuf[0][i] = make_float2(p0[i], p1[i]);
  __syncthreads();

  int cur = fft_core<N, NT>(sbuf, -1.0f, tid);

  float2* o0 = out + row0 * N;
  float2* o1 = o0 + N;
#pragma unroll
  for (int i = tid; i < N; i += NT) {
    float2 Z = sbuf[cur][i];
    float2 Zr = sbuf[cur][(N - i) & (N - 1)];
    float2 Zc = make_float2(Zr.x, -Zr.y);            // conj(Z(N-i))
    o0[i] = make_float2(0.5f * (Z.x + Zc.x), 0.5f * (Z.y + Zc.y));
    float2 dd = make_float2(Z.x - Zc.x, Z.y - Zc.y);
    o1[i] = make_float2(0.5f * dd.y, -0.5f * dd.x);  // -i*(Z-Zc)/2
  }
}

// ---------------------------------------------------------------------------
// Fused: inverse row FFT (final pass of ifft2) + first DFB fan split (axis=-1).
// Input: complex rows (already col-inverse-transformed + transposed).
// Output: s at outb[nr*W2], d at outb[halfT + nr*W2], W2 = N/2.
// ---------------------------------------------------------------------------
template <int N>
__global__ void __launch_bounds__(N / 4)
ifft_fan_k(const float2* __restrict__ in, float* __restrict__ outb,
           float scale, int halfT) {
  constexpr int NT = N / 4;
  constexpr int W2 = N / 2;
  __shared__ float2 sbuf[2][N];
  const int tid = threadIdx.x;
  const int nr = blockIdx.x;
  const int r = nr & (N - 1);
  const int par = r & 1;
  const float sgn = par ? -1.0f : 1.0f;

#pragma unroll
  for (int i = tid; i < N; i += NT) {
    float2 v = in[(size_t)nr * N + i];
    sbuf[0][i] = make_float2(v.x * scale, v.y * scale);
  }
  __syncthreads();

  int cur = fft_core<N, NT>(sbuf, 1.0f, tid);

  // xs(c) = sgn * real_row[(c+par) & (N-1)]
  float* db = (float*)sbuf[cur ^ 1];
  float* outs = outb + (size_t)nr * W2;
  float* outd = outb + halfT + (size_t)nr * W2;

#pragma unroll 2
  for (int j = tid; j < W2; j += NT) {
    float acc = 0.0f;
#pragma unroll
    for (int k = 0; k < 12; k++) {
      int c = 2 * ((j - 6 + k + W2) & (W2 - 1));
      acc += c_pkva[k] * sbuf[cur][(c + par) & (N - 1)].x;
    }
    float p1v = sbuf[cur][(2 * j + 1 + par) & (N - 1)].x;
    float dv = sgn * (p1v - acc);
    db[j] = dv;
    outd[j] = dv;
  }
  __syncthreads();
#pragma unroll 2
  for (int j = tid; j < W2; j += NT) {
    float acc = 0.0f;
#pragma unroll
    for (int k = 0; k < 12; k++)
      acc += c_pkva[k] * db[(j - 6 + k + W2) & (W2 - 1)];
    float p0v = sgn * sbuf[cur][(2 * j + par) & (N - 1)].x;
    outs[j] = p0v + 0.5f * acc;
  }
}

// Batched square transpose (per-image), complex
__global__ void transpose_k(const float2* __restrict__ in,
                            float2* __restrict__ out, int N) {
  __shared__ float2 tile[32][33];
  int img = blockIdx.z;
  size_t base = (size_t)img * N * N;
  int x = blockIdx.x * 32 + threadIdx.x;
  int y0 = blockIdx.y * 32;
  for (int j = threadIdx.y; j < 32; j += 8)
    tile[j][threadIdx.x] = in[base + (size_t)(y0 + j) * N + x];
  __syncthreads();
  int x2 = blockIdx.y * 32 + threadIdx.x;
  int y2 = blockIdx.x * 32;
  for (int j = threadIdx.y; j < 32; j += 8)
    out[base + (size_t)(y2 + j) * N + x2] = tile[threadIdx.x][j];
}

// Frequency-domain decimation by 2 with Lm mask (transposed spectra ok).
__global__ void alias_k(const float2* __restrict__ in, float2* __restrict__ out,
                        int N, int lgN2) {
  int idx = blockIdx.x * 256 + threadIdx.x;
  int N2 = N >> 1;
  int c = idx & (N2 - 1);
  int r = (idx >> lgN2) & (N2 - 1);
  int img = idx >> (2 * lgN2);
  float pr0 = phi_dev(r, N), pr1 = phi_dev(r + N2, N);
  float pc0 = phi_dev(c, N), pc1 = phi_dev(c + N2, N);
  size_t base = (size_t)img * N * N;
  float2 v00 = in[base + (size_t)r * N + c];
  float2 v01 = in[base + (size_t)r * N + c + N2];
  float2 v10 = in[base + (size_t)(r + N2) * N + c];
  float2 v11 = in[base + (size_t)(r + N2) * N + c + N2];
  float m00 = pr0 * pc0, m01 = pr0 * pc1, m10 = pr1 * pc0, m11 = pr1 * pc1;
  float2 o;
  o.x = 0.25f * (v00.x * m00 + v01.x * m01 + v10.x * m10 + v11.x * m11);
  o.y = 0.25f * (v00.y * m00 + v01.y * m01 + v10.y * m10 + v11.y * m11);
  out[((size_t)img << (2 * lgN2)) + ((size_t)r << lgN2) + c] = o;
}

// Standalone DFB fan split, axis=-1 (used mid-pipeline).
__global__ void __launch_bounds__(256)
fs_row_k(const float* __restrict__ x, float* __restrict__ outb,
         int lgH, int lgW, int halfT) {
  __shared__ float xs[1024];
  __shared__ float db[512];
  int H = 1 << lgH, W = 1 << lgW, W2 = W >> 1;
  int nr = blockIdx.x;
  int r = nr & (H - 1);
  int par = r & 1;
  float sgn = par ? -1.0f : 1.0f;
  const float* xrow = x + (size_t)nr * W;
  for (int c = threadIdx.x; c < W; c += 256)
    xs[c] = sgn * xrow[(c + par) & (W - 1)];
  __syncthreads();
  float* outs = outb + (size_t)nr * W2;
  float* outd = outb + halfT + (size_t)nr * W2;
  for (int j = threadIdx.x; j < W2; j += 256) {
    float acc = 0.0f;
#pragma unroll
    for (int k = 0; k < 12; k++)
      acc += c_pkva[k] * xs[2 * ((j - 6 + k + W2) & (W2 - 1))];
    float dv = xs[2 * j + 1] - acc;
    db[j] = dv;
    outd[j] = dv;
  }
  __syncthreads();
  for (int j = threadIdx.x; j < W2; j += 256) {
    float acc = 0.0f;
#pragma unroll
    for (int k = 0; k < 12; k++)
      acc += c_pkva[k] * db[(j - 6 + k + W2) & (W2 - 1)];
    outs[j] = xs[2 * j] + 0.5f * acc;
  }
}

// DFB fan split, axis=-2: d pass.
__global__ void __launch_bounds__(256)
fs_col_d_k(const float* __restrict__ x, float* __restrict__ outb,
           int lgH, int lgW, int halfT) {
  int H = 1 << lgH, W = 1 << lgW, H2 = H >> 1;
  int idx = blockIdx.x * 256 + threadIdx.x;
  int c = idx & (W - 1);
  int i = (idx >> lgW) & (H2 - 1);
  int n = idx >> (lgW + lgH - 1);
  int par = c & 1;
  float sgn = par ? -1.0f : 1.0f;
  const float* xim = x + ((size_t)n << (lgH + lgW));
  float p1 = xim[(((2 * i + 1 + par) & (H - 1)) << lgW) + c];
  float acc = 0.0f;
#pragma unroll
  for (int k = 0; k < 12; k++) {
    int m = (i - 6 + k + H2) & (H2 - 1);
    acc += c_pkva[k] * xim[(((2 * m + par) & (H - 1)) << lgW) + c];
  }
  outb[halfT + idx] = sgn * (p1 - acc);
}

// DFB fan split, axis=-2: s pass.
__global__ void __launch_bounds__(256)
fs_col_s_k(const float* __restrict__ x, float* __restrict__ outb,
           int lgH, int lgW, int halfT) {
  int H = 1 << lgH, W = 1 << lgW, H2 = H >> 1;
  int idx = blockIdx.x * 256 + threadIdx.x;
  int c = idx & (W - 1);
  int i = (idx >> lgW) & (H2 - 1);
  int n = idx >> (lgW + lgH - 1);
  int par = c & 1;
  float sgn = par ? -1.0f : 1.0f;
  const float* xim = x + ((size_t)n << (lgH + lgW));
  float p0 = sgn * xim[(((2 * i + par) & (H - 1)) << lgW) + c];
  float acc = 0.0f;
#pragma unroll
  for (int k = 0; k < 12; k++) {
    int m = (i - 6 + k + H2) & (H2 - 1);
    acc += c_pkva[k] * outb[halfT + ((((n << (lgH - 1)) + m) << lgW) + c)];
  }
  outb[idx] = p0 + 0.5f * acc;
}

__global__ void fill_err_k(float* out) {
  out[threadIdx.x] = 1.0e9f;
}

// ---------------------------------------------------------------------------
extern "C" void kernel_launch(void* const* d_in, const int* in_sizes, int n_in,
                              void* d_out, int out_size, void* d_ws, size_t ws_size,
                              hipStream_t stream) {
  const float* x = (const float*)d_in[0];
  float* out = (float*)d_out;
  char* ws = (char*)d_ws;

  const size_t NEED = 312475648ull;
  if (ws_size < NEED) {
    fill_err_k<<<dim3(1), dim3(256), 0, stream>>>(out);
    return;
  }

  float2* bufA  = (float2*)(ws);
  float2* bufB  = (float2*)(ws + 134217728);
  float2* spec2 = (float2*)(ws + 268435456);
  float2* spec3 = (float2*)(ws + 301989888);
  float2* spec4 = (float2*)(ws + 310378496);

  float* out0 = out;             // 262144
  float* out1 = out + 262144;    // 1048576
  float* out2 = out + 1310720;   // 4194304
  float* out3 = out + 5505024;   // 16777216

  // ---- Level 1: forward FFT2 (real-pair rows, transpose, col pass)
  rfft_pairs_k<1024><<<dim3(8192), dim3(256), 0, stream>>>(x, bufA);
  transpose_k<<<dim3(32, 32, 16), dim3(32, 8), 0, stream>>>(bufA, bufB, 1024);
  fft_rows_k<1024, 1, 0><<<dim3(16384), dim3(256), 0, stream>>>((const void*)bufB, (void*)bufA, -1.0f, 1.0f);
  alias_k<<<dim3(16384), dim3(256), 0, stream>>>(bufA, spec2, 1024, 9);
  // band1 = ifft2(X1*Hm), last pass fused with DFB fan stage 1
  fft_rows_k<1024, 2, 0><<<dim3(16384), dim3(256), 0, stream>>>((const void*)bufA, (void*)bufB, 1.0f, 1.0f / 1024.0f);
  transpose_k<<<dim3(32, 32, 16), dim3(32, 8), 0, stream>>>(bufB, bufA, 1024);
  ifft_fan_k<1024><<<dim3(16384), dim3(256), 0, stream>>>(bufA, (float*)bufB, 1.0f / 1024.0f, 8388608);
  // DFB n=4 remaining stages
  fs_col_d_k<<<dim3(32768), dim3(256), 0, stream>>>((float*)bufB, (float*)bufA, 10, 9, 8388608);
  fs_col_s_k<<<dim3(32768), dim3(256), 0, stream>>>((float*)bufB, (float*)bufA, 10, 9, 8388608);
  fs_row_k  <<<dim3(32768), dim3(256), 0, stream>>>((float*)bufA, (float*)bufB, 9, 9, 8388608);
  fs_col_d_k<<<dim3(32768), dim3(256), 0, stream>>>((float*)bufB, out3, 9, 8, 8388608);
  fs_col_s_k<<<dim3(32768), dim3(256), 0, stream>>>((float*)bufB, out3, 9, 8, 8388608);

  // ---- Level 2
  alias_k<<<dim3(4096), dim3(256), 0, stream>>>(spec2, spec3, 512, 8);
  fft_rows_k<512, 2, 0><<<dim3(8192), dim3(128), 0, stream>>>((const void*)spec2, (void*)bufA, 1.0f, 1.0f / 512.0f);
  transpose_k<<<dim3(16, 16, 16), dim3(32, 8), 0, stream>>>(bufA, bufB, 512);
  ifft_fan_k<512><<<dim3(8192), dim3(128), 0, stream>>>(bufB, (float*)bufA, 1.0f / 512.0f, 2097152);
  fs_col_d_k<<<dim3(8192),  dim3(256), 0, stream>>>((float*)bufA, (float*)bufB, 9, 8, 2097152);
  fs_col_s_k<<<dim3(8192),  dim3(256), 0, stream>>>((float*)bufA, (float*)bufB, 9, 8, 2097152);
  fs_row_k  <<<dim3(16384), dim3(256), 0, stream>>>((float*)bufB, out2, 8, 8, 2097152);

  // ---- Level 3
  alias_k<<<dim3(1024), dim3(256), 0, stream>>>(spec3, spec4, 256, 7);
  fft_rows_k<256, 2, 0><<<dim3(4096), dim3(64), 0, stream>>>((const void*)spec3, (void*)bufA, 1.0f, 1.0f / 256.0f);
  transpose_k<<<dim3(8, 8, 16), dim3(32, 8), 0, stream>>>(bufA, bufB, 256);
  ifft_fan_k<256><<<dim3(4096), dim3(64), 0, stream>>>(bufB, (float*)bufA, 1.0f / 256.0f, 524288);
  fs_col_d_k<<<dim3(2048), dim3(256), 0, stream>>>((float*)bufA, out1, 8, 7, 524288);
  fs_col_s_k<<<dim3(2048), dim3(256), 0, stream>>>((float*)bufA, out1, 8, 7, 524288);

  // ---- Final lowpass: out0 = ifft2(X4^T) at 128^2
  fft_rows_k<128, 1, 0><<<dim3(2048), dim3(32), 0, stream>>>((const void*)spec4, (void*)bufA, 1.0f, 1.0f / 128.0f);
  transpose_k<<<dim3(4, 4, 16), dim3(32, 8), 0, stream>>>(bufA, bufB, 128);
  fft_rows_k<128, 1, 1><<<dim3(2048), dim3(32), 0, stream>>>((const void*)bufB, (void*)out0, 1.0f, 1.0f / 128.0f);
}